// Round 4
// baseline (1312.159 us; speedup 1.0000x reference)
//
#include <hip/hip_runtime.h>
#include <hip/hip_bf16.h>

// Problem constants (reference: E=8, T=1024, D=2048, H=4096)
#define NE 8
#define NT 1024
#define ND 2048
#define NH 4096

typedef __attribute__((ext_vector_type(8))) short bf16x8;
typedef __attribute__((ext_vector_type(4))) float f32x4;

// async global->LDS, 16B per lane. LDS dest is wave-uniform base + lane*16 (HW).
#define ASYNC_COPY16(g, l) __builtin_amdgcn_global_load_lds( \
    (const __attribute__((address_space(1))) void*)(g),      \
    (__attribute__((address_space(3))) void*)(l), 16, 0, 0)

// ---------------- fp32 -> bf16 contiguous convert (grid-stride, G11) ----------------
__global__ __launch_bounds__(256) void convert_bf16_kernel(
    const float* __restrict__ src, __hip_bfloat16* __restrict__ dst, int n4)
{
  const int stride = gridDim.x * 256;
  for (int i = blockIdx.x * 256 + threadIdx.x; i < n4; i += stride) {
    const float4 v = reinterpret_cast<const float4*>(src)[i];
    union { ushort4 u; __hip_bfloat16 h[4]; } o;
    o.h[0] = __float2bfloat16(v.x);
    o.h[1] = __float2bfloat16(v.y);
    o.h[2] = __float2bfloat16(v.z);
    o.h[3] = __float2bfloat16(v.w);
    reinterpret_cast<ushort4*>(dst)[i] = o.u;
  }
}

// ---------------- w2 [E][H][D] fp32 -> w2t [E][D][H] bf16 ----------------
__global__ __launch_bounds__(256) void transpose_bf16_kernel(
    const float* __restrict__ src, __hip_bfloat16* __restrict__ dst)
{
  __shared__ float tile[32][33];           // +1 pad: conflict-free transpose
  const int e  = blockIdx.z;
  const int d0 = blockIdx.x * 32, h0 = blockIdx.y * 32;
  const int tx = threadIdx.x, ty = threadIdx.y;   // block (32, 8)
  const float* s = src + (size_t)e * NH * ND;
  __hip_bfloat16* t = dst + (size_t)e * ND * NH;
#pragma unroll
  for (int i = 0; i < 32; i += 8)
    tile[ty + i][tx] = s[(size_t)(h0 + ty + i) * ND + d0 + tx];
  __syncthreads();
#pragma unroll
  for (int i = 0; i < 32; i += 8)
    t[(size_t)(d0 + ty + i) * NH + h0 + tx] = __float2bfloat16(tile[tx][ty + i]);
}

// ---------------- stage1: gated = silu(x@w1^T) * (x@w3^T), bf16 out ----------------
// NT grouped GEMM, 128x128 tile, BK=32, 4 waves (2x2), dual-B sharing the A tile.
// Swizzle: expert = bid&7 (one expert per XCD), tm innermost so concurrent
// blocks on one XCD share each weight (B) tile across all 8 tm values.
__global__ __launch_bounds__(256, 2) void stage1_kernel(
    const __hip_bfloat16* __restrict__ xb,   // [E*T][D]
    const __hip_bfloat16* __restrict__ w1b,  // [E*H][D]
    const __hip_bfloat16* __restrict__ w3b,  // [E*H][D]
    __hip_bfloat16* __restrict__ gated)      // [E][T][H]
{
  constexpr int BM = 128, BN = 128, BK = 32;
  __shared__ __hip_bfloat16 lA [BM * BK];   // [128][32], row = 64B
  __shared__ __hip_bfloat16 lB1[BN * BK];
  __shared__ __hip_bfloat16 lB3[BN * BK];

  const int tid  = threadIdx.x;
  const int wave = tid >> 6, lane = tid & 63;

  constexpr int tilesM = NT / BM;             // 8
  // grid = E * tilesM * tilesN = 2048. bid&7 -> XCD/expert; tm innermost.
  const int bid = blockIdx.x;
  const int e      = bid & 7;
  const int within = bid >> 3;                // 0..255
  const int tn = within >> 3;                 // 0..31  (tilesN-1)
  const int tm = within & (tilesM - 1);       // 0..7

  const __hip_bfloat16* Ab  = xb  + ((size_t)e * NT + (size_t)tm * BM) * ND;
  const __hip_bfloat16* B1b = w1b + ((size_t)e * NH + (size_t)tn * BN) * ND;
  const __hip_bfloat16* B3b = w3b + ((size_t)e * NH + (size_t)tn * BN) * ND;

  // staging map: chunk c (1KB) holds rows [c*16, c*16+16) of a [128][32]bf16 tile.
  // lane l -> LDS byte c*1024 + l*16 -> row c*16 + (l>>2), col (l&3)*8 elems.
  const int rowL = lane >> 2;            // 0..15
  const int colL = (lane & 3) * 8;       // 0,8,16,24
  const int wr = wave >> 1, wc = wave & 1;
  // mfma_f32_16x16x32_bf16 A/B fragment: lane l holds [l&15][(l>>4)*8 + j]
  const int fRow = lane & 15, fK = (lane >> 4) * 8;

  f32x4 acc1[4][4] = {};
  f32x4 acc3[4][4] = {};

  for (int k0 = 0; k0 < ND; k0 += BK) {
#pragma unroll
    for (int i = 0; i < 2; ++i) {
      const int c = wave + i * 4;        // chunks 0..7, 2 per wave
      const int row = c * 16 + rowL;
      ASYNC_COPY16(Ab  + (size_t)row * ND + k0 + colL, (char*)lA  + c * 1024);
      ASYNC_COPY16(B1b + (size_t)row * ND + k0 + colL, (char*)lB1 + c * 1024);
      ASYNC_COPY16(B3b + (size_t)row * ND + k0 + colL, (char*)lB3 + c * 1024);
    }
    __syncthreads();   // drains vmcnt -> staged tile visible

    bf16x8 fA[4], fB1[4], fB3[4];
#pragma unroll
    for (int q = 0; q < 4; ++q) {
      fA[q]  = *(const bf16x8*)&lA [(wr * 64 + q * 16 + fRow) * BK + fK];
      fB1[q] = *(const bf16x8*)&lB1[(wc * 64 + q * 16 + fRow) * BK + fK];
      fB3[q] = *(const bf16x8*)&lB3[(wc * 64 + q * 16 + fRow) * BK + fK];
    }
#pragma unroll
    for (int im = 0; im < 4; ++im)
#pragma unroll
      for (int in = 0; in < 4; ++in) {
        acc1[im][in] = __builtin_amdgcn_mfma_f32_16x16x32_bf16(fA[im], fB1[in], acc1[im][in], 0, 0, 0);
        acc3[im][in] = __builtin_amdgcn_mfma_f32_16x16x32_bf16(fA[im], fB3[in], acc3[im][in], 0, 0, 0);
      }
    __syncthreads();   // before next iteration overwrites LDS
  }

  // epilogue: SwiGLU, store bf16. C/D map: col = lane&15, row = (lane>>4)*4 + r
  __hip_bfloat16* g = gated + (size_t)e * NT * NH;
  const int or0 = tm * BM + wr * 64;
  const int oc0 = tn * BN + wc * 64;
#pragma unroll
  for (int im = 0; im < 4; ++im)
#pragma unroll
    for (int in = 0; in < 4; ++in)
#pragma unroll
      for (int r = 0; r < 4; ++r) {
        const int row = or0 + im * 16 + (lane >> 4) * 4 + r;
        const int col = oc0 + in * 16 + (lane & 15);
        const float h1 = acc1[im][in][r];
        const float h3 = acc3[im][in][r];
        const float sw = h1 / (1.f + __expf(-h1)) * h3;   // silu(h1)*h3
        g[(size_t)row * NH + col] = __float2bfloat16(sw);
      }
}

// ---------------- stage2: out = gated @ w2  (via w2t, NT form), fp32 out ----------------
__global__ __launch_bounds__(256, 2) void stage2_kernel(
    const __hip_bfloat16* __restrict__ gated,  // [E][T][H]
    const __hip_bfloat16* __restrict__ w2t,    // [E][D][H]
    float* __restrict__ out)                   // [E*T][D]
{
  constexpr int BM = 128, BN = 128, BK = 32;
  __shared__ __hip_bfloat16 lA[BM * BK];
  __shared__ __hip_bfloat16 lB[BN * BK];

  const int tid  = threadIdx.x;
  const int wave = tid >> 6, lane = tid & 63;

  constexpr int tilesM = NT / BM;             // 8
  // grid = E * tilesM * tilesN = 1024. Same expert-per-XCD, tm-innermost map.
  const int bid = blockIdx.x;
  const int e      = bid & 7;
  const int within = bid >> 3;                // 0..127
  const int tn = within >> 3;                 // 0..15
  const int tm = within & (tilesM - 1);       // 0..7

  const __hip_bfloat16* Ab = gated + (size_t)e * NT * NH + (size_t)tm * BM * NH;
  const __hip_bfloat16* Bb = w2t   + (size_t)e * ND * NH + (size_t)tn * BN * NH;

  const int rowL = lane >> 2, colL = (lane & 3) * 8;
  const int wr = wave >> 1, wc = wave & 1;
  const int fRow = lane & 15, fK = (lane >> 4) * 8;

  f32x4 acc[4][4] = {};

  for (int k0 = 0; k0 < NH; k0 += BK) {
#pragma unroll
    for (int i = 0; i < 2; ++i) {
      const int c = wave + i * 4;
      const int row = c * 16 + rowL;
      ASYNC_COPY16(Ab + (size_t)row * NH + k0 + colL, (char*)lA + c * 1024);
      ASYNC_COPY16(Bb + (size_t)row * NH + k0 + colL, (char*)lB + c * 1024);
    }
    __syncthreads();

    bf16x8 fA[4], fB[4];
#pragma unroll
    for (int q = 0; q < 4; ++q) {
      fA[q] = *(const bf16x8*)&lA[(wr * 64 + q * 16 + fRow) * BK + fK];
      fB[q] = *(const bf16x8*)&lB[(wc * 64 + q * 16 + fRow) * BK + fK];
    }
#pragma unroll
    for (int im = 0; im < 4; ++im)
#pragma unroll
      for (int in = 0; in < 4; ++in)
        acc[im][in] = __builtin_amdgcn_mfma_f32_16x16x32_bf16(fA[im], fB[in], acc[im][in], 0, 0, 0);
    __syncthreads();
  }

  const int or0 = tm * BM + wr * 64;
  const int oc0 = tn * BN + wc * 64;
  float* obase = out + (size_t)e * NT * ND;
#pragma unroll
  for (int im = 0; im < 4; ++im)
#pragma unroll
    for (int in = 0; in < 4; ++in)
#pragma unroll
      for (int r = 0; r < 4; ++r) {
        const int row = or0 + im * 16 + (lane >> 4) * 4 + r;
        const int col = oc0 + in * 16 + (lane & 15);
        obase[(size_t)row * ND + col] = acc[im][in][r];
      }
}

extern "C" void kernel_launch(void* const* d_in, const int* in_sizes, int n_in,
                              void* d_out, int out_size, void* d_ws, size_t ws_size,
                              hipStream_t stream) {
  // dict order: x, w1, w2, w3, num_experts
  const float* x  = (const float*)d_in[0];
  const float* w1 = (const float*)d_in[1];
  const float* w2 = (const float*)d_in[2];
  const float* w3 = (const float*)d_in[3];
  float* out = (float*)d_out;

  // workspace layout (bytes):
  //   xb    [E*T*D]   bf16 :   0 ..  32MB
  //   w1b   [E*H*D]   bf16 :  32 .. 160MB
  //   w3b   [E*H*D]   bf16 : 160 .. 288MB
  //   w2t   [E*D*H]   bf16 : 288 .. 416MB
  //   gated [E*T*H]   bf16 : 416 .. 480MB
  char* ws = (char*)d_ws;
  const size_t MB = 1ull << 20;
  __hip_bfloat16* xb    = (__hip_bfloat16*)(ws);
  __hip_bfloat16* w1b   = (__hip_bfloat16*)(ws + 32 * MB);
  __hip_bfloat16* w3b   = (__hip_bfloat16*)(ws + 160 * MB);
  __hip_bfloat16* w2t   = (__hip_bfloat16*)(ws + 288 * MB);
  __hip_bfloat16* gated = (__hip_bfloat16*)(ws + 416 * MB);

  const int nx = NE * NT * ND;   // 16,777,216
  const int nw = NE * NH * ND;   // 67,108,864

  convert_bf16_kernel<<<2048, 256, 0, stream>>>(x,  xb,  nx / 4);
  convert_bf16_kernel<<<2048, 256, 0, stream>>>(w1, w1b, nw / 4);
  convert_bf16_kernel<<<2048, 256, 0, stream>>>(w3, w3b, nw / 4);
  transpose_bf16_kernel<<<dim3(ND / 32, NH / 32, NE), dim3(32, 8), 0, stream>>>(w2, w2t);

  stage1_kernel<<<NE * (NT / 128) * (NH / 128), 256, 0, stream>>>(xb, w1b, w3b, gated);
  stage2_kernel<<<NE * (NT / 128) * (ND / 128), 256, 0, stream>>>(gated, w2t, out);
}

// Round 5
// 1227.543 us; speedup vs baseline: 1.0689x; 1.0689x over previous
//
#include <hip/hip_runtime.h>
#include <hip/hip_bf16.h>

// Problem constants (reference: E=8, T=1024, D=2048, H=4096)
#define NE 8
#define NT 1024
#define ND 2048
#define NH 4096

typedef __attribute__((ext_vector_type(8))) short bf16x8;
typedef __attribute__((ext_vector_type(4))) float f32x4;

// async global->LDS, 16B per lane. LDS dest is wave-uniform base + lane*16 (HW).
#define ASYNC_COPY16(g, l) __builtin_amdgcn_global_load_lds( \
    (const __attribute__((address_space(1))) void*)(g),      \
    (__attribute__((address_space(3))) void*)(l), 16, 0, 0)

// ---------------- fp32 -> bf16 contiguous convert (grid-stride, G11) ----------------
__global__ __launch_bounds__(256) void convert_bf16_kernel(
    const float* __restrict__ src, __hip_bfloat16* __restrict__ dst, int n4)
{
  const int stride = gridDim.x * 256;
  for (int i = blockIdx.x * 256 + threadIdx.x; i < n4; i += stride) {
    const float4 v = reinterpret_cast<const float4*>(src)[i];
    union { ushort4 u; __hip_bfloat16 h[4]; } o;
    o.h[0] = __float2bfloat16(v.x);
    o.h[1] = __float2bfloat16(v.y);
    o.h[2] = __float2bfloat16(v.z);
    o.h[3] = __float2bfloat16(v.w);
    reinterpret_cast<ushort4*>(dst)[i] = o.u;
  }
}

// ---------------- w2 [E][H][D] fp32 -> w2t [E][D][H] bf16 ----------------
__global__ __launch_bounds__(256) void transpose_bf16_kernel(
    const float* __restrict__ src, __hip_bfloat16* __restrict__ dst)
{
  __shared__ float tile[32][33];           // +1 pad: conflict-free transpose
  const int e  = blockIdx.z;
  const int d0 = blockIdx.x * 32, h0 = blockIdx.y * 32;
  const int tx = threadIdx.x, ty = threadIdx.y;   // block (32, 8)
  const float* s = src + (size_t)e * NH * ND;
  __hip_bfloat16* t = dst + (size_t)e * ND * NH;
#pragma unroll
  for (int i = 0; i < 32; i += 8)
    tile[ty + i][tx] = s[(size_t)(h0 + ty + i) * ND + d0 + tx];
  __syncthreads();
#pragma unroll
  for (int i = 0; i < 32; i += 8)
    t[(size_t)(d0 + ty + i) * NH + h0 + tx] = __float2bfloat16(tile[tx][ty + i]);
}

// ===================================================================
// LDS tile: [128 rows][64 bf16 cols] = 128B/row. XOR swizzle (T2-style,
// rule #21: linear gload_lds dest + inverse-swizzled GLOBAL source +
// swizzled read). seg involution: byte ^= ((row&7)<<4).
//   staging: lane l (per wave-chunk c): LDS byte c*1024 + l*16
//            -> row = c*8 + (l>>3), src col-byte = ((l&7)^(l>>3))<<4
//   read(row, colElem): byte = row*128 + ((colElem*2) ^ ((row&7)<<4))
// Every 16-lane phase then hits all 8 segments (2 lanes each) = free.
// ===================================================================
__device__ __forceinline__ bf16x8 lds_frag(const __hip_bfloat16* base, int row, int colElem)
{
  const char* p = (const char*)base + row * 128 + ((colElem << 1) ^ ((row & 7) << 4));
  return *(const bf16x8*)p;
}

// ---------------- stage1: gated = silu(x@w1^T) * (x@w3^T), bf16 out ----------------
// NT grouped GEMM, 128x128 tile, BK=64 (32 K-steps), 4 waves (2x2), dual-B.
// Swizzle: expert = bid&7 (one expert per XCD), tm innermost for B-tile L2 reuse.
__global__ __launch_bounds__(256, 2) void stage1_kernel(
    const __hip_bfloat16* __restrict__ xb,   // [E*T][D]
    const __hip_bfloat16* __restrict__ w1b,  // [E*H][D]
    const __hip_bfloat16* __restrict__ w3b,  // [E*H][D]
    __hip_bfloat16* __restrict__ gated)      // [E][T][H]
{
  constexpr int BM = 128, BN = 128, BK = 64;
  __shared__ __hip_bfloat16 lA [BM * BK];   // 16 KB each
  __shared__ __hip_bfloat16 lB1[BN * BK];
  __shared__ __hip_bfloat16 lB3[BN * BK];

  const int tid  = threadIdx.x;
  const int wave = tid >> 6, lane = tid & 63;

  constexpr int tilesM = NT / BM;             // 8
  // grid = E * tilesM * tilesN = 2048. bid&7 -> XCD/expert; tm innermost.
  const int bid = blockIdx.x;
  const int e      = bid & 7;
  const int within = bid >> 3;                // 0..255
  const int tn = within >> 3;                 // 0..31
  const int tm = within & (tilesM - 1);       // 0..7

  const __hip_bfloat16* Ab  = xb  + ((size_t)e * NT + (size_t)tm * BM) * ND;
  const __hip_bfloat16* B1b = w1b + ((size_t)e * NH + (size_t)tn * BN) * ND;
  const __hip_bfloat16* B3b = w3b + ((size_t)e * NH + (size_t)tn * BN) * ND;

  // staging map (per 1KB chunk c): row = c*8 + (lane>>3), pre-swizzled col.
  const int srow = lane >> 3;                         // 0..7
  const int scol = ((lane & 7) ^ (lane >> 3)) << 3;   // elems, 16B-seg swizzled
  const int wr = wave >> 1, wc = wave & 1;
  // mfma_f32_16x16x32_bf16 A/B fragment: lane l holds [l&15][(l>>4)*8 + j]
  const int fRow = lane & 15, fK = (lane >> 4) * 8;

  f32x4 acc1[4][4] = {};
  f32x4 acc3[4][4] = {};

  for (int k0 = 0; k0 < ND; k0 += BK) {
#pragma unroll
    for (int p = 0; p < 4; ++p) {
      const int c = wave + p * 4;        // 16 chunks of 1KB per tile
      const int row = c * 8 + srow;
      const size_t go = (size_t)row * ND + k0 + scol;
      ASYNC_COPY16(Ab  + go, (char*)lA  + c * 1024);
      ASYNC_COPY16(B1b + go, (char*)lB1 + c * 1024);
      ASYNC_COPY16(B3b + go, (char*)lB3 + c * 1024);
    }
    __syncthreads();   // drains vmcnt -> staged tile visible

#pragma unroll
    for (int kk = 0; kk < 2; ++kk) {
      bf16x8 fA[4], fB1[4], fB3[4];
#pragma unroll
      for (int q = 0; q < 4; ++q) {
        fA[q]  = lds_frag(lA,  wr * 64 + q * 16 + fRow, kk * 32 + fK);
        fB1[q] = lds_frag(lB1, wc * 64 + q * 16 + fRow, kk * 32 + fK);
        fB3[q] = lds_frag(lB3, wc * 64 + q * 16 + fRow, kk * 32 + fK);
      }
#pragma unroll
      for (int im = 0; im < 4; ++im)
#pragma unroll
        for (int in = 0; in < 4; ++in) {
          acc1[im][in] = __builtin_amdgcn_mfma_f32_16x16x32_bf16(fA[im], fB1[in], acc1[im][in], 0, 0, 0);
          acc3[im][in] = __builtin_amdgcn_mfma_f32_16x16x32_bf16(fA[im], fB3[in], acc3[im][in], 0, 0, 0);
        }
    }
    __syncthreads();   // before next iteration overwrites LDS
  }

  // epilogue: SwiGLU, store bf16. C/D map: col = lane&15, row = (lane>>4)*4 + r
  __hip_bfloat16* g = gated + (size_t)e * NT * NH;
  const int or0 = tm * BM + wr * 64;
  const int oc0 = tn * BN + wc * 64;
#pragma unroll
  for (int im = 0; im < 4; ++im)
#pragma unroll
    for (int in = 0; in < 4; ++in)
#pragma unroll
      for (int r = 0; r < 4; ++r) {
        const int row = or0 + im * 16 + (lane >> 4) * 4 + r;
        const int col = oc0 + in * 16 + (lane & 15);
        const float h1 = acc1[im][in][r];
        const float h3 = acc3[im][in][r];
        const float sw = h1 / (1.f + __expf(-h1)) * h3;   // silu(h1)*h3
        g[(size_t)row * NH + col] = __float2bfloat16(sw);
      }
}

// ---------------- stage2: out = gated @ w2  (via w2t, NT form), fp32 out ----------------
__global__ __launch_bounds__(256, 2) void stage2_kernel(
    const __hip_bfloat16* __restrict__ gated,  // [E][T][H]
    const __hip_bfloat16* __restrict__ w2t,    // [E][D][H]
    float* __restrict__ out)                   // [E*T][D]
{
  constexpr int BM = 128, BN = 128, BK = 64;
  __shared__ __hip_bfloat16 lA[BM * BK];
  __shared__ __hip_bfloat16 lB[BN * BK];

  const int tid  = threadIdx.x;
  const int wave = tid >> 6, lane = tid & 63;

  constexpr int tilesM = NT / BM;             // 8
  // grid = E * tilesM * tilesN = 1024. Same expert-per-XCD, tm-innermost map.
  const int bid = blockIdx.x;
  const int e      = bid & 7;
  const int within = bid >> 3;                // 0..127
  const int tn = within >> 3;                 // 0..15
  const int tm = within & (tilesM - 1);       // 0..7

  const __hip_bfloat16* Ab = gated + (size_t)e * NT * NH + (size_t)tm * BM * NH;
  const __hip_bfloat16* Bb = w2t   + (size_t)e * ND * NH + (size_t)tn * BN * NH;

  const int srow = lane >> 3;
  const int scol = ((lane & 7) ^ (lane >> 3)) << 3;
  const int wr = wave >> 1, wc = wave & 1;
  const int fRow = lane & 15, fK = (lane >> 4) * 8;

  f32x4 acc[4][4] = {};

  for (int k0 = 0; k0 < NH; k0 += BK) {
#pragma unroll
    for (int p = 0; p < 4; ++p) {
      const int c = wave + p * 4;
      const int row = c * 8 + srow;
      const size_t go = (size_t)row * NH + k0 + scol;
      ASYNC_COPY16(Ab + go, (char*)lA + c * 1024);
      ASYNC_COPY16(Bb + go, (char*)lB + c * 1024);
    }
    __syncthreads();

#pragma unroll
    for (int kk = 0; kk < 2; ++kk) {
      bf16x8 fA[4], fB[4];
#pragma unroll
      for (int q = 0; q < 4; ++q) {
        fA[q] = lds_frag(lA, wr * 64 + q * 16 + fRow, kk * 32 + fK);
        fB[q] = lds_frag(lB, wc * 64 + q * 16 + fRow, kk * 32 + fK);
      }
#pragma unroll
      for (int im = 0; im < 4; ++im)
#pragma unroll
        for (int in = 0; in < 4; ++in)
          acc[im][in] = __builtin_amdgcn_mfma_f32_16x16x32_bf16(fA[im], fB[in], acc[im][in], 0, 0, 0);
    }
    __syncthreads();
  }

  const int or0 = tm * BM + wr * 64;
  const int oc0 = tn * BN + wc * 64;
  float* obase = out + (size_t)e * NT * ND;
#pragma unroll
  for (int im = 0; im < 4; ++im)
#pragma unroll
    for (int in = 0; in < 4; ++in)
#pragma unroll
      for (int r = 0; r < 4; ++r) {
        const int row = or0 + im * 16 + (lane >> 4) * 4 + r;
        const int col = oc0 + in * 16 + (lane & 15);
        obase[(size_t)row * ND + col] = acc[im][in][r];
      }
}

extern "C" void kernel_launch(void* const* d_in, const int* in_sizes, int n_in,
                              void* d_out, int out_size, void* d_ws, size_t ws_size,
                              hipStream_t stream) {
  // dict order: x, w1, w2, w3, num_experts
  const float* x  = (const float*)d_in[0];
  const float* w1 = (const float*)d_in[1];
  const float* w2 = (const float*)d_in[2];
  const float* w3 = (const float*)d_in[3];
  float* out = (float*)d_out;

  // workspace layout (bytes):
  //   xb    [E*T*D]   bf16 :   0 ..  32MB
  //   w1b   [E*H*D]   bf16 :  32 .. 160MB
  //   w3b   [E*H*D]   bf16 : 160 .. 288MB
  //   w2t   [E*D*H]   bf16 : 288 .. 416MB
  //   gated [E*T*H]   bf16 : 416 .. 480MB
  char* ws = (char*)d_ws;
  const size_t MB = 1ull << 20;
  __hip_bfloat16* xb    = (__hip_bfloat16*)(ws);
  __hip_bfloat16* w1b   = (__hip_bfloat16*)(ws + 32 * MB);
  __hip_bfloat16* w3b   = (__hip_bfloat16*)(ws + 160 * MB);
  __hip_bfloat16* w2t   = (__hip_bfloat16*)(ws + 288 * MB);
  __hip_bfloat16* gated = (__hip_bfloat16*)(ws + 416 * MB);

  const int nx = NE * NT * ND;   // 16,777,216
  const int nw = NE * NH * ND;   // 67,108,864

  convert_bf16_kernel<<<2048, 256, 0, stream>>>(x,  xb,  nx / 4);
  convert_bf16_kernel<<<2048, 256, 0, stream>>>(w1, w1b, nw / 4);
  convert_bf16_kernel<<<2048, 256, 0, stream>>>(w3, w3b, nw / 4);
  transpose_bf16_kernel<<<dim3(ND / 32, NH / 32, NE), dim3(32, 8), 0, stream>>>(w2, w2t);

  stage1_kernel<<<NE * (NT / 128) * (NH / 128), 256, 0, stream>>>(xb, w1b, w3b, gated);
  stage2_kernel<<<NE * (NT / 128) * (ND / 128), 256, 0, stream>>>(gated, w2t, out);
}